// Round 1
// baseline (810.024 us; speedup 1.0000x reference)
//
#include <hip/hip_runtime.h>

// ConvSA: B=8, C=256, H=W=48 (N=2304), E=512.
// out[b,e,i] = sum_j softmax_j(q[:,i].k[:,j]) * v[e,j] + v[e,i]
// All-fp16 operands, fp32 MFMA accumulate. Fused qkv conv (shared X tile,
// reg-prefetched staging, pre-swizzled W). Flash attention v2:
//  - i-tile 32 (O = 64 VGPR/wave), split-j x2, grid 1152, launch_bounds(256,3)
//    -> 3 blocks/CU (LDS 43 KB), no dispatch tail (2 rounds of half blocks).
//  - Phase A (QK^T) and Phase C (PV) read MFMA fragments DIRECTLY from global
//    (L2/L3-resident streams, XCD-pinned by b=bid&7): zero barriers, zero
//    staging regs, zero k/q/V LDS. Only 2 __syncthreads per jt (softmax).
//  - Softmax via LDS row-transpose (8 thr/row), P in A-frag-ordered sP2 blocks.
//  - Epilogue LDS-transposed coalesced po stores; combine() merges 2 j-halves.

typedef _Float16 f16;
typedef _Float16 f16x4 __attribute__((ext_vector_type(4)));
typedef _Float16 f16x8 __attribute__((ext_vector_type(8)));
typedef float    f32x4  __attribute__((ext_vector_type(4)));
typedef float    f32x16 __attribute__((ext_vector_type(16)));

__device__ __forceinline__ f32x16 mfma16(f16x8 a, f16x8 b, f32x16 c) {
  return __builtin_amdgcn_mfma_f32_32x32x16_f16(a, b, c, 0, 0, 0);
}

#define NB   8
#define NC   256
#define NH   48
#define NN   2304     // 48*48
#define NE   512
#define HP   50       // padded H/W

// ---------------- pack kernels ----------------

// feat NCHW fp32 -> zero-padded NHWC [b][50][50][256] fp16
__global__ void pack_feat(const float* __restrict__ x, f16* __restrict__ p) {
  int idx = blockIdx.x * 256 + threadIdx.x;       // 8*50*50*256
  int c  = idx & 255;
  int q  = idx >> 8;
  int xp = q % 50; int t = q / 50; int yp = t % 50; int b = t / 50;
  float v = 0.f;
  if (yp >= 1 && yp <= 48 && xp >= 1 && xp <= 48)
    v = x[((b * NC + c) * NH + (yp - 1)) * NH + (xp - 1)];
  p[idx] = (f16)v;
}

// W OIHW [512][256][3][3] fp32 -> A-frag blocks:
// [cc 16][t 9][et 16] x (el 32 x cl 16) contiguous 512-f16 (1 KB) blocks.
__global__ void pack_w(const float* __restrict__ wq, const float* __restrict__ wk,
                       const float* __restrict__ wv,
                       f16* __restrict__ oq, f16* __restrict__ ok,
                       f16* __restrict__ ov) {
  int idx = blockIdx.x * 256 + threadIdx.x;       // 9*512*256
  int c = idx & 255;
  int r = idx >> 8;
  int e = r & 511; int t = r >> 9;
  int src = (e * NC + c) * 9 + t;
  int cc = c >> 4, cl = c & 15, et = e >> 5, el = e & 31;
  int dst = ((cc * 9 + t) * 16 + et) * 512 + el * 16 + cl;
  oq[dst] = (f16)wq[src];
  ok[dst] = (f16)wk[src];
  ov[dst] = (f16)wv[src];
}

// ---------------- fused implicit-GEMM conv3x3 for q,k,v ----------------
// Block 256 thr; out tile 32 e x 384 pos x {q,k,v}; grid (16 e-tiles, 48).
__global__ __launch_bounds__(256, 2) void conv3_qkv(
    const f16* __restrict__ xh,
    const f16* __restrict__ wq, const f16* __restrict__ wk,
    const f16* __restrict__ wv,
    const float* __restrict__ bq, const float* __restrict__ bk,
    const float* __restrict__ bv,
    f16* __restrict__ oq, f16* __restrict__ ok, f16* __restrict__ ov) {
  __shared__ __align__(16) f16 sx[12000];         // 10*50*24

  const int tid = threadIdx.x;
  const int lane = tid & 63, wvx = tid >> 6;
  const int l31 = lane & 31;
  const int koff = (lane >> 5) * 8;
  const int et = blockIdx.x;
  const int e0 = et * 32;
  const int by = blockIdx.y;
  const int b = by / 6, strip = by % 6;
  const int y0 = strip * 8;

  int pb[3];
#pragma unroll
  for (int nt = 0; nt < 3; ++nt) {
    int n = wvx * 96 + nt * 32 + l31;
    pb[nt] = (n / 48) * 50 + (n % 48);
  }

  // staging coords: 4 chunks/thread
  int sgp[4], sgo[4]; bool sok[4]; int gbase[4];
#pragma unroll
  for (int u = 0; u < 4; ++u) {
    int g = u * 256 + tid;
    sok[u] = (g < 1000);
    int gg = sok[u] ? g : 999;
    sgp[u] = gg >> 1; sgo[u] = (gg & 1) * 8;
    int row = sgp[u] / 50, xx = sgp[u] % 50;
    gbase[u] = ((b * HP + y0 + row) * HP + xx) * NC + sgo[u];
  }

  f32x16 acc[3][3];                               // [qkv][nt]
#pragma unroll
  for (int f = 0; f < 3; ++f)
#pragma unroll
    for (int nt = 0; nt < 3; ++nt)
#pragma unroll
      for (int i = 0; i < 16; ++i) acc[f][nt][i] = 0.f;

  f16x8 rx[4];
#pragma unroll
  for (int u = 0; u < 4; ++u)
    rx[u] = *(const f16x8*)(xh + gbase[u]);       // cc=0 prefetch

  const int wlocal = l31 * 16 + koff;

  for (int cc = 0; cc < 16; ++cc) {
    __syncthreads();                              // prev compute done
#pragma unroll
    for (int u = 0; u < 4; ++u)
      if (sok[u]) *(f16x8*)(sx + sgp[u] * 24 + sgo[u]) = rx[u];
    __syncthreads();
    if (cc < 15) {                                // overlap next loads w/ compute
      int c0 = (cc + 1) * 16;
#pragma unroll
      for (int u = 0; u < 4; ++u)
        rx[u] = *(const f16x8*)(xh + gbase[u] + c0);
    }
#pragma unroll
    for (int t = 0; t < 9; ++t) {
      const int dy = t / 3, dx = t % 3;
      const int dpo = (dy * 50 + dx) * 24 + koff;
      f16x8 bh[3];
#pragma unroll
      for (int nt = 0; nt < 3; ++nt)
        bh[nt] = *(const f16x8*)(sx + pb[nt] * 24 + dpo);
      int wb = ((cc * 9 + t) * 16 + et) * 512 + wlocal;
      f16x8 aq = *(const f16x8*)(wq + wb);
      f16x8 ak = *(const f16x8*)(wk + wb);
      f16x8 av = *(const f16x8*)(wv + wb);
#pragma unroll
      for (int nt = 0; nt < 3; ++nt) {
        acc[0][nt] = mfma16(aq, bh[nt], acc[0][nt]);
        acc[1][nt] = mfma16(ak, bh[nt], acc[1][nt]);
        acc[2][nt] = mfma16(av, bh[nt], acc[2][nt]);
      }
    }
  }

  // epilogue: C/D layout col=lane&31 (=pos), row=(r&3)+8*(r>>2)+4*(lane>>5) (=e)
  const int colh = (lane >> 5) * 4;
#pragma unroll
  for (int nt = 0; nt < 3; ++nt) {
    int n = wvx * 96 + nt * 32 + l31;
    int pos = (y0 + n / 48) * 48 + (n % 48);
#pragma unroll
    for (int g = 0; g < 4; ++g) {
      int eb = e0 + g * 8 + colh;
      f32x4 sq = *(const f32x4*)(bq + eb);
      f32x4 sk = *(const f32x4*)(bk + eb);
      f32x4 sv = *(const f32x4*)(bv + eb);
      f16x4 hq, hk;
#pragma unroll
      for (int j = 0; j < 4; ++j) {
        hq[j] = (f16)(acc[0][nt][g * 4 + j] + sq[j]);
        hk[j] = (f16)(acc[1][nt][g * 4 + j] + sk[j]);
        ov[(b * NE + eb + j) * NN + pos] = (f16)(acc[2][nt][g * 4 + j] + sv[j]);
      }
      *(f16x4*)(oq + (b * NN + pos) * NE + eb) = hq;
      *(f16x4*)(ok + (b * NN + pos) * NE + eb) = hk;
    }
  }
}

// ---------------- flash attention (fp16, split-j x2, i-tile 32) ----------------
// Grid 1152: b = bid&7 (XCD swizzle), jh = (bid>>3)&1, i-tile = bid>>4 (32 rows).
// Per wave: S covers 32 i x 32 j (wave wvx owns j-quarter), O covers 32 i x 128 e
// (wave wvx owns e-slice wvx*128). q/k/v fragments read directly from global
// (L2-resident, full-line consumption across ks). Only LDS: softmax transpose
// (sS, 32x132 f32), P A-frag blocks (sP2), epilogue transpose (sT, aliases sS).
__global__ __launch_bounds__(256, 3) void attn(
    const f16* __restrict__ qt, const f16* __restrict__ kt,
    const f16* __restrict__ vt, f16* __restrict__ po,
    float* __restrict__ pm, float* __restrict__ pl) {
  __shared__ __align__(16) f16 sR[17408];   // sS: 32x132 f32 (16.9KB) | sT: 4x(128x34) f16 (34.8KB)
  __shared__ __align__(16) f16 sP2[4096];   // 16 blocks x (32 slots x 8 f16) = 8KB
  __shared__ __align__(16) float s_m[32];
  __shared__ __align__(16) float s_l[32];
  __shared__ __align__(16) float s_alpha[32];

  const int tid = threadIdx.x;
  const int lane = tid & 63, wvx = tid >> 6;
  const int l31 = lane & 31, lh = lane >> 5;
  const int bid = blockIdx.x;
  const int b = bid & 7;
  const int jh = (bid >> 3) & 1;
  const int i0 = (bid >> 4) * 32;

  const size_t qbase = ((size_t)b * NN + i0) * NE;
  const size_t kbase = (size_t)b * NN * NE;
  const size_t vbase = (size_t)b * NE * NN;

  if (tid < 32) { s_m[tid] = -3.0e38f; s_l[tid] = 0.f; }

  f32x16 O[4];
#pragma unroll
  for (int nt = 0; nt < 4; ++nt)
#pragma unroll
    for (int i = 0; i < 16; ++i) O[nt][i] = 0.f;

  const int rrow = tid >> 3, qd = tid & 7;        // Phase-B: 8 threads per i-row
  float* sS = (float*)sR;

  // A-frag base: lane holds A[i = l31][e = ec*64 + ks*16 + lh*8 ..+7]
  const f16* qp = qt + qbase + (size_t)l31 * NE + lh * 8;

  for (int jt = 0; jt < 9; ++jt) {
    const int j0 = jh * 1152 + jt * 128;
    f32x16 S;
#pragma unroll
    for (int i = 0; i < 16; ++i) S[i] = 0.f;

    // ---- Phase A: S = q.k^T, fully unrolled direct-global stream (no barriers)
    const f16* kp = kt + kbase + (size_t)(j0 + wvx * 32 + l31) * NE + lh * 8;
#pragma unroll
    for (int ec = 0; ec < 8; ++ec) {
      f16x8 aq[4], bk[4];
#pragma unroll
      for (int ks = 0; ks < 4; ++ks) {
        aq[ks] = *(const f16x8*)(qp + ec * 64 + ks * 16);
        bk[ks] = *(const f16x8*)(kp + ec * 64 + ks * 16);
      }
#pragma unroll
      for (int ks = 0; ks < 4; ++ks)
        S = mfma16(aq[ks], bk[ks], S);
    }

    // ---- Phase B: softmax via LDS row-transpose ----
    // dump S: row i = (r&3)+8*(r>>2)+4*lh, col j = wvx*32 + l31
#pragma unroll
    for (int r = 0; r < 16; ++r) {
      int ii = (r & 3) + 8 * (r >> 2) + 4 * lh;
      sS[ii * 132 + wvx * 32 + l31] = S[r];
    }
    __syncthreads();   // dump visible; also fences prev Phase C sP2 reads

    float vals[16];
#pragma unroll
    for (int c = 0; c < 2; ++c) {
      f32x4 a0 = *(const f32x4*)(sS + rrow * 132 + qd * 8 + 64 * c);
      f32x4 a1 = *(const f32x4*)(sS + rrow * 132 + qd * 8 + 64 * c + 4);
#pragma unroll
      for (int u = 0; u < 4; ++u) {
        vals[c * 8 + u] = a0[u];
        vals[c * 8 + 4 + u] = a1[u];
      }
    }
    float mx = vals[0];
#pragma unroll
    for (int u = 1; u < 16; ++u) mx = fmaxf(mx, vals[u]);
    mx = fmaxf(mx, __shfl_xor(mx, 1, 64));
    mx = fmaxf(mx, __shfl_xor(mx, 2, 64));
    mx = fmaxf(mx, __shfl_xor(mx, 4, 64));
    float mold = s_m[rrow];
    float mnew = fmaxf(mold, mx);
    float alpha = __expf(mold - mnew);
    float sum = 0.f;
#pragma unroll
    for (int c = 0; c < 2; ++c) {
      f16x8 pc;
#pragma unroll
      for (int u = 0; u < 8; ++u) {
        f16 ph = (f16)__expf(vals[c * 8 + u] - mnew);
        pc[u] = ph;
        sum += (float)ph;
      }
      // j = qd*8 + c*64 + u  ->  k-slice kc = (qd>>1)+4c, half = qd&1
      int KB = ((qd >> 1) + 4 * c) * 2 + (qd & 1);
      *(f16x8*)(sP2 + KB * 256 + (((rrow + KB * 4) & 31) * 8)) = pc;
    }
    sum += __shfl_xor(sum, 1, 64);
    sum += __shfl_xor(sum, 2, 64);
    sum += __shfl_xor(sum, 4, 64);
    if (qd == 0) {
      s_alpha[rrow] = alpha;
      s_m[rrow] = mnew;
      s_l[rrow] = s_l[rrow] * alpha + sum;
    }
    __syncthreads();

    // rescale O: i = (r&3)+8*(r>>2)+4*lh
#pragma unroll
    for (int g = 0; g < 4; ++g) {
      f32x4 al = *(const f32x4*)(s_alpha + g * 8 + 4 * lh);
#pragma unroll
      for (int j2 = 0; j2 < 4; ++j2) {
        float a = al[j2];
#pragma unroll
        for (int nt = 0; nt < 4; ++nt) O[nt][g * 4 + j2] *= a;
      }
    }

    // ---- Phase C: O += P.V^T, direct-global V fragments (no barriers) ----
    // B-frag: lane holds V[e = wvx*128 + nt*32 + l31][j = jc*32 + ks*16 + lh*8]
    const f16* vp = vt + vbase + (size_t)(wvx * 128 + l31) * NN + j0 + lh * 8;
#pragma unroll
    for (int jc = 0; jc < 4; ++jc) {
      f16x8 ap[2], bv[2][4];
#pragma unroll
      for (int ks = 0; ks < 2; ++ks) {
        int KB = (jc * 2 + ks) * 2 + lh;
        ap[ks] = *(const f16x8*)(sP2 + KB * 256 + (((l31 + KB * 4) & 31) * 8));
#pragma unroll
        for (int nt = 0; nt < 4; ++nt)
          bv[ks][nt] = *(const f16x8*)(vp + (size_t)(nt * 32) * NN + jc * 32 + ks * 16);
      }
#pragma unroll
      for (int ks = 0; ks < 2; ++ks)
#pragma unroll
        for (int nt = 0; nt < 4; ++nt)
          O[nt] = mfma16(ap[ks], bv[ks][nt], O[nt]);
    }
  }

  // ---- epilogue: m,l + LDS-transposed coalesced po stores ----
  __syncthreads();                                // all sS/sP2 readers done
  if (tid < 32) {
    pm[(jh * NB + b) * NN + i0 + tid] = s_m[tid];
    pl[(jh * NB + b) * NN + i0 + tid] = s_l[tid];
  }
  const size_t pobase = ((size_t)(jh * NB + b) * NE) * NN;
  f16* sT = sR + wvx * 4352;                      // 128 e x stride 34 f16 / wave
#pragma unroll
  for (int nt = 0; nt < 4; ++nt) {
    int el = nt * 32 + l31;
#pragma unroll
    for (int g = 0; g < 4; ++g) {
      f16x4 h4;
#pragma unroll
      for (int j2 = 0; j2 < 4; ++j2)
        h4[j2] = (f16)O[nt][g * 4 + j2];
      *(f16x4*)(sT + el * 34 + g * 8 + 4 * lh) = h4;
    }
  }
#pragma unroll
  for (int rr = 0; rr < 16; ++rr) {
    int el = rr * 8 + (lane >> 3);
    int iq = lane & 7;
    f16x4 t4 = *(const f16x4*)(sT + el * 34 + iq * 4);
    *(f16x4*)(po + pobase + (size_t)(wvx * 128 + el) * NN + i0 + iq * 4) = t4;
  }
}

// ---------------- combine: merge 2 j-halves, divide, add v ----------------
__global__ void combine(const f16* __restrict__ po, const float* __restrict__ pm,
                        const float* __restrict__ pl, const f16* __restrict__ vt,
                        float* __restrict__ out) {
  int id = blockIdx.x * 256 + threadIdx.x;        // NB*NE*NN/4
  int base = id * 4;
  int i  = base % NN;
  int eb = base / NN;                             // b*NE + e
  int b  = eb >> 9;
  const size_t H = (size_t)NB * NE * NN;
  f32x4 m0 = *(const f32x4*)(pm + b * NN + i);
  f32x4 m1 = *(const f32x4*)(pm + NB * NN + b * NN + i);
  f32x4 l0 = *(const f32x4*)(pl + b * NN + i);
  f32x4 l1 = *(const f32x4*)(pl + NB * NN + b * NN + i);
  f16x4 a0 = *(const f16x4*)(po + (size_t)eb * NN + i);
  f16x4 a1 = *(const f16x4*)(po + H + (size_t)eb * NN + i);
  f16x4 vv = *(const f16x4*)(vt + (size_t)eb * NN + i);
  f32x4 res;
#pragma unroll
  for (int j = 0; j < 4; ++j) {
    float m = fmaxf(m0[j], m1[j]);
    float w0 = __expf(m0[j] - m), w1 = __expf(m1[j] - m);
    float l = w0 * l0[j] + w1 * l1[j];
    res[j] = (w0 * (float)a0[j] + w1 * (float)a1[j]) / l + (float)vv[j];
  }
  *(f32x4*)(out + (size_t)eb * NN + i) = res;
}

// ---------------- launch ----------------
extern "C" void kernel_launch(void* const* d_in, const int* in_sizes, int n_in,
                              void* d_out, int out_size, void* d_ws, size_t ws_size,
                              hipStream_t stream) {
  const float* feat = (const float*)d_in[0];
  const float* Wq = (const float*)d_in[1];
  const float* bq = (const float*)d_in[2];
  const float* Wk = (const float*)d_in[3];
  const float* bk = (const float*)d_in[4];
  const float* Wv = (const float*)d_in[5];
  const float* bv = (const float*)d_in[6];
  float* out = (float*)d_out;

  char* ws = (char*)d_ws;
  size_t off = 0;
  auto alloc = [&](size_t bytes) {
    void* p = ws + off;
    off += (bytes + 255) & ~(size_t)255;
    return p;
  };
  const size_t FP = (size_t)NB * HP * HP * NC;     // 5,120,000
  const size_t WP = (size_t)9 * NE * NC;           // 1,179,648
  const size_t QP = (size_t)NB * NN * NE;          // 9,437,184
  f16* fp  = (f16*)alloc(FP * 2);
  f16* wq  = (f16*)alloc(WP * 2);
  f16* wk  = (f16*)alloc(WP * 2);
  f16* wv  = (f16*)alloc(WP * 2);
  f16* q_t = (f16*)alloc(QP * 2);
  f16* k_t = (f16*)alloc(QP * 2);
  f16* v_t = (f16*)alloc(QP * 2);
  f16* po  = (f16*)alloc(2 * QP * 2);              // 37.7 MB partial O
  float* pm = (float*)alloc(2 * (size_t)NB * NN * 4);
  float* pl = (float*)alloc(2 * (size_t)NB * NN * 4);

  pack_feat<<<dim3(FP / 256), dim3(256), 0, stream>>>(feat, fp);
  pack_w<<<dim3(WP / 256), dim3(256), 0, stream>>>(Wq, Wk, Wv, wq, wk, wv);

  conv3_qkv<<<dim3(16, 48), dim3(256), 0, stream>>>(
      fp, wq, wk, wv, bq, bk, bv, q_t, k_t, v_t);

  attn<<<dim3(1152), dim3(256), 0, stream>>>(q_t, k_t, v_t, po, pm, pl);
  combine<<<dim3((NB * NE * NN / 4) / 256), dim3(256), 0, stream>>>(po, pm, pl, v_t, out);
}

// Round 2
// 616.514 us; speedup vs baseline: 1.3139x; 1.3139x over previous
//
#include <hip/hip_runtime.h>

// ConvSA: B=8, C=256, H=W=48 (N=2304), E=512.
// out[b,e,i] = sum_j softmax_j(q[:,i].k[:,j]) * v[e,j] + v[e,i]
// All-fp16 operands, fp32 MFMA accumulate. Fused qkv conv (shared X tile,
// reg-prefetched staging, pre-swizzled W). Flash attention v3:
//  - i-tile 32, NO j-split: grid 576 (8b x 72 i-tiles), launch_bounds(256,3)
//    -> 3 blocks/CU, ALL blocks resident (no dispatch tail), 12 waves/CU
//    cover each other's barrier drains.
//  - R0-style cooperative LDS staging restored for q/k (dbuf 64-e chunks) and
//    V (wave-private, single-buffered regs prefetched under the softmax
//    reduce) -> full-line global reads, no beyond-L2 overfetch (R1 lesson).
//  - Softmax via LDS row-transpose (8 thr/row), P in A-frag-ordered sP2.
//  - Epilogue normalizes by 1/l in-register and writes FINAL fp32 out
//    (+v residual) via LDS transpose -> combine kernel and po/pm/pl deleted.

typedef _Float16 f16;
typedef _Float16 f16x4 __attribute__((ext_vector_type(4)));
typedef _Float16 f16x8 __attribute__((ext_vector_type(8)));
typedef float    f32x4  __attribute__((ext_vector_type(4)));
typedef float    f32x16 __attribute__((ext_vector_type(16)));

__device__ __forceinline__ f32x16 mfma16(f16x8 a, f16x8 b, f32x16 c) {
  return __builtin_amdgcn_mfma_f32_32x32x16_f16(a, b, c, 0, 0, 0);
}

#define NB   8
#define NC   256
#define NH   48
#define NN   2304     // 48*48
#define NE   512
#define HP   50       // padded H/W

// ---------------- pack kernels ----------------

// feat NCHW fp32 -> zero-padded NHWC [b][50][50][256] fp16
__global__ void pack_feat(const float* __restrict__ x, f16* __restrict__ p) {
  int idx = blockIdx.x * 256 + threadIdx.x;       // 8*50*50*256
  int c  = idx & 255;
  int q  = idx >> 8;
  int xp = q % 50; int t = q / 50; int yp = t % 50; int b = t / 50;
  float v = 0.f;
  if (yp >= 1 && yp <= 48 && xp >= 1 && xp <= 48)
    v = x[((b * NC + c) * NH + (yp - 1)) * NH + (xp - 1)];
  p[idx] = (f16)v;
}

// W OIHW [512][256][3][3] fp32 -> A-frag blocks:
// [cc 16][t 9][et 16] x (el 32 x cl 16) contiguous 512-f16 (1 KB) blocks.
__global__ void pack_w(const float* __restrict__ wq, const float* __restrict__ wk,
                       const float* __restrict__ wv,
                       f16* __restrict__ oq, f16* __restrict__ ok,
                       f16* __restrict__ ov) {
  int idx = blockIdx.x * 256 + threadIdx.x;       // 9*512*256
  int c = idx & 255;
  int r = idx >> 8;
  int e = r & 511; int t = r >> 9;
  int src = (e * NC + c) * 9 + t;
  int cc = c >> 4, cl = c & 15, et = e >> 5, el = e & 31;
  int dst = ((cc * 9 + t) * 16 + et) * 512 + el * 16 + cl;
  oq[dst] = (f16)wq[src];
  ok[dst] = (f16)wk[src];
  ov[dst] = (f16)wv[src];
}

// ---------------- fused implicit-GEMM conv3x3 for q,k,v ----------------
// Block 256 thr; out tile 32 e x 384 pos x {q,k,v}; grid (16 e-tiles, 48).
__global__ __launch_bounds__(256, 2) void conv3_qkv(
    const f16* __restrict__ xh,
    const f16* __restrict__ wq, const f16* __restrict__ wk,
    const f16* __restrict__ wv,
    const float* __restrict__ bq, const float* __restrict__ bk,
    const float* __restrict__ bv,
    f16* __restrict__ oq, f16* __restrict__ ok, f16* __restrict__ ov) {
  __shared__ __align__(16) f16 sx[12000];         // 10*50*24

  const int tid = threadIdx.x;
  const int lane = tid & 63, wvx = tid >> 6;
  const int l31 = lane & 31;
  const int koff = (lane >> 5) * 8;
  const int et = blockIdx.x;
  const int e0 = et * 32;
  const int by = blockIdx.y;
  const int b = by / 6, strip = by % 6;
  const int y0 = strip * 8;

  int pb[3];
#pragma unroll
  for (int nt = 0; nt < 3; ++nt) {
    int n = wvx * 96 + nt * 32 + l31;
    pb[nt] = (n / 48) * 50 + (n % 48);
  }

  // staging coords: 4 chunks/thread
  int sgp[4], sgo[4]; bool sok[4]; int gbase[4];
#pragma unroll
  for (int u = 0; u < 4; ++u) {
    int g = u * 256 + tid;
    sok[u] = (g < 1000);
    int gg = sok[u] ? g : 999;
    sgp[u] = gg >> 1; sgo[u] = (gg & 1) * 8;
    int row = sgp[u] / 50, xx = sgp[u] % 50;
    gbase[u] = ((b * HP + y0 + row) * HP + xx) * NC + sgo[u];
  }

  f32x16 acc[3][3];                               // [qkv][nt]
#pragma unroll
  for (int f = 0; f < 3; ++f)
#pragma unroll
    for (int nt = 0; nt < 3; ++nt)
#pragma unroll
      for (int i = 0; i < 16; ++i) acc[f][nt][i] = 0.f;

  f16x8 rx[4];
#pragma unroll
  for (int u = 0; u < 4; ++u)
    rx[u] = *(const f16x8*)(xh + gbase[u]);       // cc=0 prefetch

  const int wlocal = l31 * 16 + koff;

  for (int cc = 0; cc < 16; ++cc) {
    __syncthreads();                              // prev compute done
#pragma unroll
    for (int u = 0; u < 4; ++u)
      if (sok[u]) *(f16x8*)(sx + sgp[u] * 24 + sgo[u]) = rx[u];
    __syncthreads();
    if (cc < 15) {                                // overlap next loads w/ compute
      int c0 = (cc + 1) * 16;
#pragma unroll
      for (int u = 0; u < 4; ++u)
        rx[u] = *(const f16x8*)(xh + gbase[u] + c0);
    }
#pragma unroll
    for (int t = 0; t < 9; ++t) {
      const int dy = t / 3, dx = t % 3;
      const int dpo = (dy * 50 + dx) * 24 + koff;
      f16x8 bh[3];
#pragma unroll
      for (int nt = 0; nt < 3; ++nt)
        bh[nt] = *(const f16x8*)(sx + pb[nt] * 24 + dpo);
      int wb = ((cc * 9 + t) * 16 + et) * 512 + wlocal;
      f16x8 aq = *(const f16x8*)(wq + wb);
      f16x8 ak = *(const f16x8*)(wk + wb);
      f16x8 av = *(const f16x8*)(wv + wb);
#pragma unroll
      for (int nt = 0; nt < 3; ++nt) {
        acc[0][nt] = mfma16(aq, bh[nt], acc[0][nt]);
        acc[1][nt] = mfma16(ak, bh[nt], acc[1][nt]);
        acc[2][nt] = mfma16(av, bh[nt], acc[2][nt]);
      }
    }
  }

  // epilogue: C/D layout col=lane&31 (=pos), row=(r&3)+8*(r>>2)+4*(lane>>5) (=e)
  const int colh = (lane >> 5) * 4;
#pragma unroll
  for (int nt = 0; nt < 3; ++nt) {
    int n = wvx * 96 + nt * 32 + l31;
    int pos = (y0 + n / 48) * 48 + (n % 48);
#pragma unroll
    for (int g = 0; g < 4; ++g) {
      int eb = e0 + g * 8 + colh;
      f32x4 sq = *(const f32x4*)(bq + eb);
      f32x4 sk = *(const f32x4*)(bk + eb);
      f32x4 sv = *(const f32x4*)(bv + eb);
      f16x4 hq, hk;
#pragma unroll
      for (int j = 0; j < 4; ++j) {
        hq[j] = (f16)(acc[0][nt][g * 4 + j] + sq[j]);
        hk[j] = (f16)(acc[1][nt][g * 4 + j] + sk[j]);
        ov[(b * NE + eb + j) * NN + pos] = (f16)(acc[2][nt][g * 4 + j] + sv[j]);
      }
      *(f16x4*)(oq + (b * NN + pos) * NE + eb) = hq;
      *(f16x4*)(ok + (b * NN + pos) * NE + eb) = hk;
    }
  }
}

// ---------------- flash attention (fp16, i-tile 32, no j-split) ----------------
// Grid 576: b = bid&7 (XCD swizzle), i-tile = bid>>3 (32 rows). 18 jt of 128.
// Per wave: S = 32 i x 32 j (wave owns j-quarter); O = 32 i x 128 e (e-slice).
// Phase A: q/k staged via dbuf 64-e LDS chunks (full-line global reads).
// Phase B: softmax via LDS row-transpose; P -> A-frag sP2 blocks.
// Phase C: V wave-private LDS (single-buffered regs, jc0 prefetched in B).
// Epilogue: O/l + v -> final fp32 out via per-wave LDS transpose.
__global__ __launch_bounds__(256, 3) void attn(
    const f16* __restrict__ qt, const f16* __restrict__ kt,
    const f16* __restrict__ vt, float* __restrict__ out) {
  __shared__ __align__(16) f16 sA[20480];   // q dbuf 2x2048 | k dbuf 2x8192 @4096
                                            // aliases: sS f32[32][132] (16.9KB),
                                            // svw/sT wave-private wvx*5120
  __shared__ __align__(16) f16 sP2[4096];   // 16 blocks x (32 slots x 8 f16) = 8KB
  __shared__ __align__(16) float s_m[32];
  __shared__ __align__(16) float s_l[32];
  __shared__ __align__(16) float s_alpha[32];

  const int tid = threadIdx.x;
  const int lane = tid & 63, wvx = tid >> 6;
  const int l31 = lane & 31, lh = lane >> 5;
  const int bid = blockIdx.x;
  const int b = bid & 7;
  const int i0 = (bid >> 3) * 32;

  const size_t qbase = ((size_t)b * NN + i0) * NE;
  const size_t kbase = (size_t)b * NN * NE;
  const size_t vbase = (size_t)b * NE * NN;
  f16* svw = sA + wvx * 5120;                     // wave-private V / sT region

  if (tid < 32) { s_m[tid] = -3.0e38f; s_l[tid] = 0.f; }

  f32x16 O[4];
#pragma unroll
  for (int nt = 0; nt < 4; ++nt)
#pragma unroll
    for (int i = 0; i < 16; ++i) O[nt][i] = 0.f;

  const int srow = tid >> 3, scol8 = tid & 7;     // q/k staging coords
  const int rrow = srow, qd = scol8;              // Phase-B row ownership
  float* sS = (float*)sA;
  const int jrow = wvx * 32 + l31;

  for (int jt = 0; jt < 18; ++jt) {
    const int j0 = jt * 128;
    f32x16 S;
#pragma unroll
    for (int i = 0; i < 16; ++i) S[i] = 0.f;

    // prologue: prefetch e-chunk 0, barrier (prev Phase C svw reads done), store
    f16x8 rq = *(const f16x8*)(qt + qbase + (size_t)srow * NE + scol8 * 8);
    f16x8 rk[4];
#pragma unroll
    for (int r = 0; r < 4; ++r)
      rk[r] = *(const f16x8*)(kt + kbase + (size_t)(j0 + srow + r * 32) * NE + scol8 * 8);
    __syncthreads();
    *(f16x8*)(sA + srow * 64 + ((scol8 ^ (srow & 7)) * 8)) = rq;
#pragma unroll
    for (int r = 0; r < 4; ++r) {
      int row = srow + r * 32;
      *(f16x8*)(sA + 4096 + row * 64 + ((scol8 ^ (row & 7)) * 8)) = rk[r];
    }

    // ---- Phase A: S = q.k^T, 8 e-chunks of 64, double-buffered ----
    for (int ec = 0; ec < 8; ++ec) {
      __syncthreads();
      const bool pf = (ec < 7);
      if (pf) {
        rq = *(const f16x8*)(qt + qbase + (size_t)srow * NE + (ec + 1) * 64 + scol8 * 8);
#pragma unroll
        for (int r = 0; r < 4; ++r)
          rk[r] = *(const f16x8*)(kt + kbase + (size_t)(j0 + srow + r * 32) * NE + (ec + 1) * 64 + scol8 * 8);
      }
      const int qcur = (ec & 1) * 2048;
      const int kcur = 4096 + (ec & 1) * 8192;
      f16x8 aq[4];
#pragma unroll
      for (int ks = 0; ks < 4; ++ks)
        aq[ks] = *(const f16x8*)(sA + qcur + l31 * 64 + (((ks * 2 + lh) ^ (l31 & 7)) * 8));
#pragma unroll
      for (int ks = 0; ks < 4; ++ks) {
        f16x8 bk = *(const f16x8*)(sA + kcur + jrow * 64 + (((ks * 2 + lh) ^ (jrow & 7)) * 8));
        S = mfma16(aq[ks], bk, S);
      }
      if (pf) {
        const int qn = ((ec + 1) & 1) * 2048;
        const int kn = 4096 + ((ec + 1) & 1) * 8192;
        *(f16x8*)(sA + qn + srow * 64 + ((scol8 ^ (srow & 7)) * 8)) = rq;
#pragma unroll
        for (int r = 0; r < 4; ++r) {
          int row = srow + r * 32;
          *(f16x8*)(sA + kn + row * 64 + ((scol8 ^ (row & 7)) * 8)) = rk[r];
        }
      }
    }

    // ---- Phase B: softmax via LDS row-transpose ----
    __syncthreads();                  // Phase-A q/k LDS reads done (sS aliases!)
#pragma unroll
    for (int r = 0; r < 16; ++r) {
      int ii = (r & 3) + 8 * (r >> 2) + 4 * lh;
      sS[ii * 132 + wvx * 32 + l31] = S[r];
    }
    __syncthreads();

    // prefetch V chunk jc=0 (hidden under the reduction)
    f16x8 rv[8];
#pragma unroll
    for (int r = 0; r < 8; ++r) {
      int gr = lane * 8 + r;
      int row = gr >> 2, of = (gr & 3) * 8;
      rv[r] = *(const f16x8*)(vt + vbase + (size_t)(wvx * 128 + row) * NN + j0 + of);
    }

    float vals[16];
#pragma unroll
    for (int c = 0; c < 2; ++c) {
      f32x4 a0 = *(const f32x4*)(sS + rrow * 132 + qd * 8 + 64 * c);
      f32x4 a1 = *(const f32x4*)(sS + rrow * 132 + qd * 8 + 64 * c + 4);
#pragma unroll
      for (int u = 0; u < 4; ++u) {
        vals[c * 8 + u] = a0[u];
        vals[c * 8 + 4 + u] = a1[u];
      }
    }
    float mx = vals[0];
#pragma unroll
    for (int u = 1; u < 16; ++u) mx = fmaxf(mx, vals[u]);
    mx = fmaxf(mx, __shfl_xor(mx, 1, 64));
    mx = fmaxf(mx, __shfl_xor(mx, 2, 64));
    mx = fmaxf(mx, __shfl_xor(mx, 4, 64));
    float mold = s_m[rrow];
    float mnew = fmaxf(mold, mx);
    float alpha = __expf(mold - mnew);
    float sum = 0.f;
#pragma unroll
    for (int c = 0; c < 2; ++c) {
      f16x8 pc;
#pragma unroll
      for (int u = 0; u < 8; ++u) {
        f16 ph = (f16)__expf(vals[c * 8 + u] - mnew);
        pc[u] = ph;
        sum += (float)ph;
      }
      // j = qd*8 + c*64 + u  ->  KB = (granule16)*2 + sub8
      int KB = ((qd >> 1) + 4 * c) * 2 + (qd & 1);
      *(f16x8*)(sP2 + KB * 256 + (((rrow + KB * 4) & 31) * 8)) = pc;
    }
    sum += __shfl_xor(sum, 1, 64);
    sum += __shfl_xor(sum, 2, 64);
    sum += __shfl_xor(sum, 4, 64);
    if (qd == 0) {
      s_alpha[rrow] = alpha;
      s_m[rrow] = mnew;
      s_l[rrow] = s_l[rrow] * alpha + sum;
    }
    __syncthreads();

    // rescale O: i = g*8 + 4*lh + j2
#pragma unroll
    for (int g = 0; g < 4; ++g) {
      f32x4 al = *(const f32x4*)(s_alpha + g * 8 + 4 * lh);
#pragma unroll
      for (int j2 = 0; j2 < 4; ++j2) {
        float a = al[j2];
#pragma unroll
        for (int nt = 0; nt < 4; ++nt) O[nt][g * 4 + j2] *= a;
      }
    }

    // ---- Phase C: O += P.V^T, V via wave-private LDS, no barriers ----
#pragma unroll
    for (int jc = 0; jc < 4; ++jc) {
#pragma unroll
      for (int r = 0; r < 8; ++r) {
        int gr = lane * 8 + r;
        int row = gr >> 2, of = (gr & 3) * 8;
        *(f16x8*)(svw + row * 40 + of) = rv[r];
      }
      if (jc < 3) {
#pragma unroll
        for (int r = 0; r < 8; ++r) {
          int gr = lane * 8 + r;
          int row = gr >> 2, of = (gr & 3) * 8;
          rv[r] = *(const f16x8*)(vt + vbase + (size_t)(wvx * 128 + row) * NN + j0 + (jc + 1) * 32 + of);
        }
      }
#pragma unroll
      for (int ks = 0; ks < 2; ++ks) {
        int KB = (jc * 2 + ks) * 2 + lh;
        f16x8 ap = *(const f16x8*)(sP2 + KB * 256 + (((l31 + KB * 4) & 31) * 8));
#pragma unroll
        for (int nt = 0; nt < 4; ++nt) {
          f16x8 bv = *(const f16x8*)(svw + (nt * 32 + l31) * 40 + ks * 16 + lh * 8);
          O[nt] = mfma16(ap, bv, O[nt]);
        }
      }
    }
  }

  // ---- epilogue: normalize by 1/l, add v, final fp32 out (coalesced) ----
  // s_l final + visible (post-reduce barrier of last jt). svw/sT wave-private.
#pragma unroll
  for (int g = 0; g < 4; ++g) {
    f32x4 lv = *(const f32x4*)(s_l + g * 8 + 4 * lh);
#pragma unroll
    for (int j2 = 0; j2 < 4; ++j2) {
      float inv = 1.0f / lv[j2];
#pragma unroll
      for (int nt = 0; nt < 4; ++nt) O[nt][g * 4 + j2] *= inv;
    }
  }
  f16* sT = svw;                                  // 128 e x stride 36 f16 / wave
#pragma unroll
  for (int nt = 0; nt < 4; ++nt) {
    int el = nt * 32 + l31;
#pragma unroll
    for (int g = 0; g < 4; ++g) {
      f16x4 h4;
#pragma unroll
      for (int j2 = 0; j2 < 4; ++j2)
        h4[j2] = (f16)O[nt][g * 4 + j2];
      *(f16x4*)(sT + el * 36 + g * 8 + 4 * lh) = h4;
    }
  }
#pragma unroll
  for (int rr = 0; rr < 16; ++rr) {
    int el = rr * 8 + (lane >> 3);
    int iq = lane & 7;
    f16x4 t4 = *(const f16x4*)(sT + el * 36 + iq * 4);
    f16x4 vv = *(const f16x4*)(vt + vbase + (size_t)(wvx * 128 + el) * NN + i0 + iq * 4);
    f32x4 res;
#pragma unroll
    for (int j = 0; j < 4; ++j)
      res[j] = (float)t4[j] + (float)vv[j];
    *(f32x4*)(out + ((size_t)b * NE + wvx * 128 + el) * NN + i0 + iq * 4) = res;
  }
}

// ---------------- launch ----------------
extern "C" void kernel_launch(void* const* d_in, const int* in_sizes, int n_in,
                              void* d_out, int out_size, void* d_ws, size_t ws_size,
                              hipStream_t stream) {
  const float* feat = (const float*)d_in[0];
  const float* Wq = (const float*)d_in[1];
  const float* bq = (const float*)d_in[2];
  const float* Wk = (const float*)d_in[3];
  const float* bk = (const float*)d_in[4];
  const float* Wv = (const float*)d_in[5];
  const float* bv = (const float*)d_in[6];
  float* out = (float*)d_out;

  char* ws = (char*)d_ws;
  size_t off = 0;
  auto alloc = [&](size_t bytes) {
    void* p = ws + off;
    off += (bytes + 255) & ~(size_t)255;
    return p;
  };
  const size_t FP = (size_t)NB * HP * HP * NC;     // 5,120,000
  const size_t WP = (size_t)9 * NE * NC;           // 1,179,648
  const size_t QP = (size_t)NB * NN * NE;          // 9,437,184
  f16* fp  = (f16*)alloc(FP * 2);
  f16* wq  = (f16*)alloc(WP * 2);
  f16* wk  = (f16*)alloc(WP * 2);
  f16* wv  = (f16*)alloc(WP * 2);
  f16* q_t = (f16*)alloc(QP * 2);
  f16* k_t = (f16*)alloc(QP * 2);
  f16* v_t = (f16*)alloc(QP * 2);

  pack_feat<<<dim3(FP / 256), dim3(256), 0, stream>>>(feat, fp);
  pack_w<<<dim3(WP / 256), dim3(256), 0, stream>>>(Wq, Wk, Wv, wq, wk, wv);

  conv3_qkv<<<dim3(16, 48), dim3(256), 0, stream>>>(
      fp, wq, wk, wv, bq, bk, bv, q_t, k_t, v_t);

  attn<<<dim3(576), dim3(256), 0, stream>>>(q_t, k_t, v_t, out);
}

// Round 3
// 447.454 us; speedup vs baseline: 1.8103x; 1.3778x over previous
//
#include <hip/hip_runtime.h>

// ConvSA: B=8, C=256, H=W=48 (N=2304), E=512.
// out[b,e,i] = sum_j softmax_j(q[:,i].k[:,j]) * v[e,j] + v[e,i]
// Flash attention v4 (barrier-minimal):
//  - Swapped QK^T: S = mfma(k_frag, q_frag) -> D col = i. Softmax is
//    lane-local (m, l, alpha in registers, per-lane scalars). No sS LDS.
//  - conv writes k_f / v_f in MFMA A-frag block layout (contiguous 1KB per
//    wave-load): Phase A streams k from global (L2), Phase C streams v.
//    No k/v LDS staging, no Phase A/C barriers. 2 barriers per jt (softmax
//    partial exchanges, 512 B each).
//  - q tile (32x512) loaded to LDS ONCE per block (swizzled, persistent).
//  - P packed to B-frags in-register (shfl_xor 32 quad exchange), shared
//    across waves via 8 KB sP2 (linear, conflict-free).
//  - Epilogue: per-lane 1/l normalize + v residual, direct coalesced fp32
//    stores (lanes = consecutive i). No LDS transpose, no combine kernel.

typedef _Float16 f16;
typedef _Float16 f16x4 __attribute__((ext_vector_type(4)));
typedef _Float16 f16x8 __attribute__((ext_vector_type(8)));
typedef float    f32x4  __attribute__((ext_vector_type(4)));
typedef float    f32x16 __attribute__((ext_vector_type(16)));

__device__ __forceinline__ f32x16 mfma16(f16x8 a, f16x8 b, f32x16 c) {
  return __builtin_amdgcn_mfma_f32_32x32x16_f16(a, b, c, 0, 0, 0);
}

#define NB   8
#define NC   256
#define NH   48
#define NN   2304     // 48*48
#define NE   512
#define HP   50       // padded H/W
#define QSTR 528      // q_lds row stride (f16), padded

// ---------------- pack kernels ----------------

// feat NCHW fp32 -> zero-padded NHWC [b][50][50][256] fp16
__global__ void pack_feat(const float* __restrict__ x, f16* __restrict__ p) {
  int idx = blockIdx.x * 256 + threadIdx.x;       // 8*50*50*256
  int c  = idx & 255;
  int q  = idx >> 8;
  int xp = q % 50; int t = q / 50; int yp = t % 50; int b = t / 50;
  float v = 0.f;
  if (yp >= 1 && yp <= 48 && xp >= 1 && xp <= 48)
    v = x[((b * NC + c) * NH + (yp - 1)) * NH + (xp - 1)];
  p[idx] = (f16)v;
}

// W OIHW [512][256][3][3] fp32 -> A-frag blocks:
// [cc 16][t 9][et 16] x (el 32 x cl 16) contiguous 512-f16 (1 KB) blocks.
__global__ void pack_w(const float* __restrict__ wq, const float* __restrict__ wk,
                       const float* __restrict__ wv,
                       f16* __restrict__ oq, f16* __restrict__ ok,
                       f16* __restrict__ ov) {
  int idx = blockIdx.x * 256 + threadIdx.x;       // 9*512*256
  int c = idx & 255;
  int r = idx >> 8;
  int e = r & 511; int t = r >> 9;
  int src = (e * NC + c) * 9 + t;
  int cc = c >> 4, cl = c & 15, et = e >> 5, el = e & 31;
  int dst = ((cc * 9 + t) * 16 + et) * 512 + el * 16 + cl;
  oq[dst] = (f16)wq[src];
  ok[dst] = (f16)wk[src];
  ov[dst] = (f16)wv[src];
}

// ---------------- fused implicit-GEMM conv3x3 for q,k,v ----------------
// Block 256 thr; out tile 32 e x 384 pos x {q,k,v}; grid (16 e-tiles, 48).
// q -> row-major [pos][e]; k -> k_f frag blocks [b][j/32][e/16][lane64][8];
// v -> v_f frag blocks [b][e/32][j/16][lane64][8].
__global__ __launch_bounds__(256, 2) void conv3_qkv(
    const f16* __restrict__ xh,
    const f16* __restrict__ wq, const f16* __restrict__ wk,
    const f16* __restrict__ wv,
    const float* __restrict__ bq, const float* __restrict__ bk,
    const float* __restrict__ bv,
    f16* __restrict__ oq, f16* __restrict__ kf, f16* __restrict__ vf) {
  __shared__ __align__(16) f16 sx[12000];         // 10*50*24

  const int tid = threadIdx.x;
  const int lane = tid & 63, wvx = tid >> 6;
  const int l31 = lane & 31;
  const int koff = (lane >> 5) * 8;
  const int et = blockIdx.x;
  const int e0 = et * 32;
  const int by = blockIdx.y;
  const int b = by / 6, strip = by % 6;
  const int y0 = strip * 8;

  int pb[3];
#pragma unroll
  for (int nt = 0; nt < 3; ++nt) {
    int n = wvx * 96 + nt * 32 + l31;
    pb[nt] = (n / 48) * 50 + (n % 48);
  }

  // staging coords: 4 chunks/thread
  int sgp[4], sgo[4]; bool sok[4]; int gbase[4];
#pragma unroll
  for (int u = 0; u < 4; ++u) {
    int g = u * 256 + tid;
    sok[u] = (g < 1000);
    int gg = sok[u] ? g : 999;
    sgp[u] = gg >> 1; sgo[u] = (gg & 1) * 8;
    int row = sgp[u] / 50, xx = sgp[u] % 50;
    gbase[u] = ((b * HP + y0 + row) * HP + xx) * NC + sgo[u];
  }

  f32x16 acc[3][3];                               // [qkv][nt]
#pragma unroll
  for (int f = 0; f < 3; ++f)
#pragma unroll
    for (int nt = 0; nt < 3; ++nt)
#pragma unroll
      for (int i = 0; i < 16; ++i) acc[f][nt][i] = 0.f;

  f16x8 rx[4];
#pragma unroll
  for (int u = 0; u < 4; ++u)
    rx[u] = *(const f16x8*)(xh + gbase[u]);       // cc=0 prefetch

  const int wlocal = l31 * 16 + koff;

  for (int cc = 0; cc < 16; ++cc) {
    __syncthreads();                              // prev compute done
#pragma unroll
    for (int u = 0; u < 4; ++u)
      if (sok[u]) *(f16x8*)(sx + sgp[u] * 24 + sgo[u]) = rx[u];
    __syncthreads();
    if (cc < 15) {                                // overlap next loads w/ compute
      int c0 = (cc + 1) * 16;
#pragma unroll
      for (int u = 0; u < 4; ++u)
        rx[u] = *(const f16x8*)(xh + gbase[u] + c0);
    }
#pragma unroll
    for (int t = 0; t < 9; ++t) {
      const int dy = t / 3, dx = t % 3;
      const int dpo = (dy * 50 + dx) * 24 + koff;
      f16x8 bh[3];
#pragma unroll
      for (int nt = 0; nt < 3; ++nt)
        bh[nt] = *(const f16x8*)(sx + pb[nt] * 24 + dpo);
      int wb = ((cc * 9 + t) * 16 + et) * 512 + wlocal;
      f16x8 aq = *(const f16x8*)(wq + wb);
      f16x8 ak = *(const f16x8*)(wk + wb);
      f16x8 av = *(const f16x8*)(wv + wb);
#pragma unroll
      for (int nt = 0; nt < 3; ++nt) {
        acc[0][nt] = mfma16(aq, bh[nt], acc[0][nt]);
        acc[1][nt] = mfma16(ak, bh[nt], acc[1][nt]);
        acc[2][nt] = mfma16(av, bh[nt], acc[2][nt]);
      }
    }
  }

  // epilogue: C/D layout col=lane&31 (=pos), row=(r&3)+8*(r>>2)+4*(lane>>5) (=e)
  const int colh = (lane >> 5) * 4;
#pragma unroll
  for (int nt = 0; nt < 3; ++nt) {
    int n = wvx * 96 + nt * 32 + l31;
    int pos = (y0 + n / 48) * 48 + (n % 48);
    const int jblk = pos >> 5, jl = pos & 31;
    const int jc = pos >> 4, lhv = (pos >> 3) & 1, uv = pos & 7;
#pragma unroll
    for (int g = 0; g < 4; ++g) {
      int eb = e0 + g * 8 + colh;
      f32x4 sq = *(const f32x4*)(bq + eb);
      f32x4 sk = *(const f32x4*)(bk + eb);
      f32x4 sv = *(const f32x4*)(bv + eb);
      f16x4 hq, hk;
#pragma unroll
      for (int j = 0; j < 4; ++j) {
        hq[j] = (f16)(acc[0][nt][g * 4 + j] + sq[j]);
        hk[j] = (f16)(acc[1][nt][g * 4 + j] + sk[j]);
        int e = eb + j;
        // v_f: [b][e>>5][pos>>4][((pos>>3)&1)*32 + (e&31)][pos&7]
        vf[((((size_t)b * 16 + (e >> 5)) * 144 + jc) * 64 + lhv * 32 + (e & 31)) * 8 + uv] =
            (f16)(acc[2][nt][g * 4 + j] + sv[j]);
      }
      // k_f: [b][pos>>5][eb>>4][((eb>>3)&1)*32 + (pos&31)][eb&7 .. +3]
      *(f16x4*)(kf + ((((size_t)b * 72 + jblk) * 32 + (eb >> 4)) * 64 +
                      ((eb >> 3) & 1) * 32 + jl) * 8 + (eb & 7)) = hk;
      *(f16x4*)(oq + ((size_t)b * NN + pos) * NE + eb) = hq;
    }
  }
}

// ---------------- flash attention v4 ----------------
// Grid 576: b = bid&7 (XCD pin), i-tile = bid>>3 (32 rows). 18 jt of 128 j.
// Per wave: S covers (wave's 32-j block) x (32 i); O covers 128 e x 32 i.
// Phase A: k streamed from global frag blocks (reg pipeline, no barriers),
//          q from persistent LDS. Phase B: lane-local softmax + 2 tiny LDS
//          exchanges (the only 2 barriers). Phase C: v streamed from global,
//          P from sP2. Epilogue: per-lane normalize + residual, direct store.
__global__ __launch_bounds__(256, 3) void attn(
    const f16* __restrict__ qt, const f16* __restrict__ kf,
    const f16* __restrict__ vf, float* __restrict__ out) {
  __shared__ __align__(16) f16 q_lds[32 * QSTR];  // 33792 B, persistent
  __shared__ __align__(16) f16 sP2[4096];         // 8 chunks x 64 lanes x 8 f16
  __shared__ __align__(16) float s_pmax[128];
  __shared__ __align__(16) float s_psum[128];

  const int tid = threadIdx.x;
  const int lane = tid & 63, wvx = tid >> 6;
  const int l31 = lane & 31, lh = lane >> 5;
  const int bid = blockIdx.x;
  const int b = bid & 7;
  const int i0 = (bid >> 3) * 32;

  // ---- load q tile (32 x 512) once, swizzled ----
  {
    const f16* qb = qt + ((size_t)b * NN + i0) * NE;
#pragma unroll
    for (int it = 0; it < 8; ++it) {
      int g = it * 256 + tid;
      int row = g >> 6, gr = g & 63;
      f16x8 v = *(const f16x8*)(qb + row * NE + gr * 8);
      int sgr = (gr & ~7) | ((gr & 7) ^ (row & 7));
      *(f16x8*)(q_lds + row * QSTR + sgr * 8) = v;
    }
  }
  __syncthreads();

  float m_reg = -1e30f, l_reg = 0.f;
  f32x16 O[4];
#pragma unroll
  for (int nt = 0; nt < 4; ++nt)
#pragma unroll
    for (int i = 0; i < 16; ++i) O[nt][i] = 0.f;

  const int x7 = l31 & 7;
  const f16* kfw = kf + (size_t)(b * 72 + wvx) * 16384 + lane * 8;
  const f16* vfw = vf + (size_t)(b * 16 + wvx * 4) * 73728 + lane * 8;
  const f16* qrow = q_lds + l31 * QSTR;

  for (int jt = 0; jt < 18; ++jt) {
    // ---- Phase A: S = k.q^T (swapped) — no barriers ----
    const f16* kfl = kfw + (size_t)jt * 4 * 16384;
    f32x16 S0, S1;
#pragma unroll
    for (int i = 0; i < 16; ++i) { S0[i] = 0.f; S1[i] = 0.f; }
    f16x8 kpipe[6];
#pragma unroll
    for (int t = 0; t < 6; ++t) kpipe[t] = *(const f16x8*)(kfl + t * 512);
    f16x8 qpipe[2];
#pragma unroll
    for (int t = 0; t < 2; ++t) {
      int ga = t * 2 + lh;
      int sg = (ga & ~7) | ((ga & 7) ^ x7);
      qpipe[t] = *(const f16x8*)(qrow + sg * 8);
    }
#pragma unroll
    for (int c = 0; c < 32; ++c) {
      f16x8 ak = kpipe[c % 6];
      if (c + 6 < 32) kpipe[c % 6] = *(const f16x8*)(kfl + (c + 6) * 512);
      f16x8 aq = qpipe[c & 1];
      if (c + 2 < 32) {
        int ga = (c + 2) * 2 + lh;
        int sg = (ga & ~7) | ((ga & 7) ^ x7);
        qpipe[c & 1] = *(const f16x8*)(qrow + sg * 8);
      }
      if (c & 1) S1 = mfma16(ak, aq, S1);
      else       S0 = mfma16(ak, aq, S0);
    }
    f32x16 S;
#pragma unroll
    for (int r = 0; r < 16; ++r) S[r] = S0[r] + S1[r];
    // lane (i=l31, h=lh) holds S[i][j_local = (r&3)+8*(r>>2)+4*lh] for wave's
    // j-block = jt*128 + wvx*32.

    // ---- Phase B: lane-local softmax, 2 barriers ----
    float wmax = S[0];
#pragma unroll
    for (int r = 1; r < 16; ++r) wmax = fmaxf(wmax, S[r]);
    wmax = fmaxf(wmax, __shfl_xor(wmax, 32, 64));
    if (lane < 32) s_pmax[l31 * 4 + wvx] = wmax;
    __syncthreads();                              // barrier 1 (also fences sP2)
    f32x4 pm4 = *(const f32x4*)(s_pmax + l31 * 4);
    float gmax = fmaxf(fmaxf(pm4[0], pm4[1]), fmaxf(pm4[2], pm4[3]));
    float mnew = fmaxf(m_reg, gmax);
    float alpha = __expf(m_reg - mnew);
    m_reg = mnew;

    f16 ph[16];
    float psum = 0.f;
#pragma unroll
    for (int r = 0; r < 16; ++r) {
      f16 p = (f16)__expf(S[r] - mnew);
      ph[r] = p;
      psum += (float)p;
    }
    // pack quads -> B-frags via cross-half exchange, write sP2
    union Q4 { f16x4 h; int i2[2]; };
    Q4 q4[4];
#pragma unroll
    for (int t = 0; t < 4; ++t)
#pragma unroll
      for (int u = 0; u < 4; ++u) q4[t].h[u] = ph[t * 4 + u];
#pragma unroll
    for (int ks = 0; ks < 2; ++ks) {
      Q4 t1, t2;
      t1.i2[0] = __shfl_xor(q4[2 * ks + 1].i2[0], 32, 64);
      t1.i2[1] = __shfl_xor(q4[2 * ks + 1].i2[1], 32, 64);
      t2.i2[0] = __shfl_xor(q4[2 * ks].i2[0], 32, 64);
      t2.i2[1] = __shfl_xor(q4[2 * ks].i2[1], 32, 64);
      f16x4 first  = lh ? t1.h : q4[2 * ks].h;
      f16x4 second = lh ? q4[2 * ks + 1].h : t2.h;
      f16x8 frag;
#pragma unroll
      for (int u = 0; u < 4; ++u) { frag[u] = first[u]; frag[4 + u] = second[u]; }
      *(f16x8*)(sP2 + ((wvx * 2 + ks) * 64 + lane) * 8) = frag;
    }
    psum += __shfl_xor(psum, 32, 64);
    if (lane < 32) s_psum[l31 * 4 + wvx] = psum;
    // rescale O while the exchange settles
#pragma unroll
    for (int nt = 0; nt < 4; ++nt)
#pragma unroll
      for (int r = 0; r < 16; ++r) O[nt][r] *= alpha;
    __syncthreads();                              // barrier 2 (P + sums visible)
    f32x4 ps4 = *(const f32x4*)(s_psum + l31 * 4);
    l_reg = l_reg * alpha + (ps4[0] + ps4[1] + ps4[2] + ps4[3]);

    // ---- Phase C: O += V.P (A=v frag stream, B=P from sP2) — no barriers ----
    const f16* vfl = vfw + (size_t)jt * 8 * 512;
    f16x8 vpipe[6];
#pragma unroll
    for (int t = 0; t < 6; ++t) {
      int nt = t & 3, cg = t >> 2;
      vpipe[t] = *(const f16x8*)(vfl + (size_t)nt * 73728 + cg * 512);
    }
    f16x8 apc = *(const f16x8*)(sP2 + (0 * 64 + lane) * 8);
    f16x8 apn = *(const f16x8*)(sP2 + (1 * 64 + lane) * 8);
#pragma unroll
    for (int c = 0; c < 32; ++c) {
      int nt = c & 3, cg = c >> 2;
      f16x8 av = vpipe[c % 6];
      if (c + 6 < 32) {
        int nt2 = (c + 6) & 3, cg2 = (c + 6) >> 2;
        vpipe[c % 6] = *(const f16x8*)(vfl + (size_t)nt2 * 73728 + cg2 * 512);
      }
      O[nt] = mfma16(av, apc, O[nt]);
      if (nt == 3) {
        apc = apn;
        if (cg + 2 < 8) apn = *(const f16x8*)(sP2 + ((cg + 2) * 64 + lane) * 8);
      }
    }
  }

  // ---- epilogue: per-lane normalize + v residual, direct coalesced stores ----
  float inv = 1.0f / l_reg;
  const int ii = i0 + l31;
  const int jcR = ii >> 4, lhR = (ii >> 3) & 1, uR = ii & 7;
#pragma unroll
  for (int nt = 0; nt < 4; ++nt) {
    const f16* vres = vf + ((((size_t)(b * 16 + wvx * 4 + nt)) * 144 + jcR) * 64 + lhR * 32) * 8 + uR;
    const int ebase = wvx * 128 + nt * 32;
#pragma unroll
    for (int r = 0; r < 16; ++r) {
      int el = (r & 3) + 8 * (r >> 2) + 4 * lh;
      float rv = (float)vres[el * 8];
      out[((size_t)b * NE + ebase + el) * NN + ii] = O[nt][r] * inv + rv;
    }
  }
}

// ---------------- launch ----------------
extern "C" void kernel_launch(void* const* d_in, const int* in_sizes, int n_in,
                              void* d_out, int out_size, void* d_ws, size_t ws_size,
                              hipStream_t stream) {
  const float* feat = (const float*)d_in[0];
  const float* Wq = (const float*)d_in[1];
  const float* bq = (const float*)d_in[2];
  const float* Wk = (const float*)d_in[3];
  const float* bk = (const float*)d_in[4];
  const float* Wv = (const float*)d_in[5];
  const float* bv = (const float*)d_in[6];
  float* out = (float*)d_out;

  char* ws = (char*)d_ws;
  size_t off = 0;
  auto alloc = [&](size_t bytes) {
    void* p = ws + off;
    off += (bytes + 255) & ~(size_t)255;
    return p;
  };
  const size_t FP = (size_t)NB * HP * HP * NC;     // 5,120,000
  const size_t WP = (size_t)9 * NE * NC;           // 1,179,648
  const size_t QP = (size_t)NB * NN * NE;          // 9,437,184
  f16* fp  = (f16*)alloc(FP * 2);
  f16* wq  = (f16*)alloc(WP * 2);
  f16* wk  = (f16*)alloc(WP * 2);
  f16* wv  = (f16*)alloc(WP * 2);
  f16* q_t = (f16*)alloc(QP * 2);
  f16* k_f = (f16*)alloc(QP * 2);
  f16* v_f = (f16*)alloc(QP * 2);

  pack_feat<<<dim3(FP / 256), dim3(256), 0, stream>>>(feat, fp);
  pack_w<<<dim3(WP / 256), dim3(256), 0, stream>>>(Wq, Wk, Wv, wq, wk, wv);

  conv3_qkv<<<dim3(16, 48), dim3(256), 0, stream>>>(
      fp, wq, wk, wv, bq, bk, bv, q_t, k_f, v_f);

  attn<<<dim3(576), dim3(256), 0, stream>>>(q_t, k_f, v_f, out);
}